// Round 2
// baseline (821.519 us; speedup 1.0000x reference)
//
#include <hip/hip_runtime.h>
#include <hip/hip_bf16.h>

typedef unsigned int u32;
typedef unsigned short u16;

#define LRELU_SLOPE 0.2f

__device__ inline float bfbits(u32 hi) { union { u32 i; float f; } v; v.i = hi; return v.f; }
__device__ inline float bflo(u32 w) { return bfbits(w << 16); }
__device__ inline float bfhi(u32 w) { return bfbits(w & 0xFFFF0000u); }
__device__ inline float bf2f(u16 s) { return bfbits(((u32)s) << 16); }
__device__ inline u16 f2bf(float f) {
  union { float f; u32 i; } v; v.f = f;
  u32 r = v.i + 0x7FFFu + ((v.i >> 16) & 1u); // round-to-nearest-even
  return (u16)(r >> 16);
}

// ------------------------------------------------ dtype sniff: bf16-packed vs f32
// f32 N(0,1) data: low 16 bits are uniform mantissa bits -> exp-field window hit ~14%.
// packed bf16 data: low u16 IS a bf16 N(0,1) value -> window hit ~100%.
__global__ void detect_kernel(const u32* __restrict__ g, int nwords, int* __restrict__ mode) {
  __shared__ int cnt;
  if (threadIdx.x == 0) cnt = 0;
  __syncthreads();
  int c = 0;
  for (int i = threadIdx.x; i < nwords; i += blockDim.x) {
    u32 e = g[i] & 0x7F80u; // exponent field of the LOW u16 viewed as bf16
    if (e >= 0x3000u && e <= 0x4180u) c++;
  }
  atomicAdd(&cnt, c);
  __syncthreads();
  if (threadIdx.x == 0) *mode = (2 * cnt > nwords) ? 1 : 0; // 1 = inputs are bf16
}

// ------------------------------------------------ input normalization
__global__ void conv_x_kernel(const void* __restrict__ g, u16* __restrict__ x, int n,
                              const int* __restrict__ mode) {
  int i = blockIdx.x * blockDim.x + threadIdx.x;
  if (i >= n) return;
  if (*mode) x[i] = ((const u16*)g)[i];
  else       x[i] = f2bf(((const float*)g)[i]);
}

// pf layout: [0,4096) W row-major, [4096,4160) att_src, [4160,4224) att_dst, [4224,4288) bias
__global__ void conv_params_kernel(const void* __restrict__ W, const void* __restrict__ as,
                                   const void* __restrict__ ad, const void* __restrict__ bs,
                                   float* __restrict__ pf, const int* __restrict__ mode) {
  int i = blockIdx.x * blockDim.x + threadIdx.x;
  if (i >= 4288) return;
  const void* p; int j;
  if (i < 4096)      { p = W;  j = i; }
  else if (i < 4160) { p = as; j = i - 4096; }
  else if (i < 4224) { p = ad; j = i - 4160; }
  else               { p = bs; j = i - 4224; }
  pf[i] = (*mode) ? bf2f(((const u16*)p)[j]) : ((const float*)p)[j];
}

// ------------------------------------------------ CSR build
__global__ void hist_kernel(const int* __restrict__ dst, int* __restrict__ deg, int E) {
  int i = blockIdx.x * blockDim.x + threadIdx.x;
  if (i < E) atomicAdd(&deg[dst[i]], 1);
}

__global__ void scan1_kernel(const int* __restrict__ deg, int* __restrict__ row_off,
                             int* __restrict__ partials, int N) {
  __shared__ int smem[1024];
  int t = threadIdx.x;
  int idx = blockIdx.x * 1024 + t;
  int v = (idx < N) ? deg[idx] : 0;
  smem[t] = v;
  __syncthreads();
  for (int off = 1; off < 1024; off <<= 1) {
    int u = (t >= off) ? smem[t - off] : 0;
    __syncthreads();
    smem[t] += u;
    __syncthreads();
  }
  if (idx < N) row_off[idx + 1] = smem[t];
  if (t == 1023) partials[blockIdx.x] = smem[t];
}

__global__ void scan2_kernel(int* __restrict__ partials, int P) {
  __shared__ int smem[1024];
  int t = threadIdx.x;
  int v = (t < P) ? partials[t] : 0;
  smem[t] = v;
  __syncthreads();
  for (int off = 1; off < 1024; off <<= 1) {
    int u = (t >= off) ? smem[t - off] : 0;
    __syncthreads();
    smem[t] += u;
    __syncthreads();
  }
  if (t < P) partials[t] = smem[t];
}

__global__ void scan3_kernel(int* __restrict__ row_off, const int* __restrict__ partials, int N) {
  int b = blockIdx.x;
  int idx = b * 1024 + threadIdx.x;
  if (b > 0 && idx < N) row_off[idx + 1] += partials[b - 1];
  if (idx == 0) row_off[0] = 0;
}

__global__ void scatter_kernel(const int* __restrict__ src, const int* __restrict__ dst,
                               int* __restrict__ cursor, int* __restrict__ csr_src, int E) {
  int i = blockIdx.x * blockDim.x + threadIdx.x;
  if (i < E) {
    int p = atomicAdd(&cursor[dst[i]], 1);
    csr_src[p] = src[i];
  }
}

// ------------------------------------------------ h = x@W, a_src = h.att_s, a_dst = h.att_d
// One wave per row; lane j holds W[:,j] in 64 VGPRs; x row read as uniform 16B loads.
__global__ void __launch_bounds__(256) proj_kernel(
    const u16* __restrict__ x, const float* __restrict__ pf,
    u16* __restrict__ h, float* __restrict__ a_src, float* __restrict__ a_dst, int N) {
  int lane = threadIdx.x & 63;
  int wid = (int)((blockIdx.x * blockDim.x + threadIdx.x) >> 6);
  int nwaves = (int)((gridDim.x * blockDim.x) >> 6);

  float Wc[64];
#pragma unroll
  for (int k = 0; k < 64; ++k) Wc[k] = pf[k * 64 + lane];
  float as = pf[4096 + lane];
  float ad = pf[4160 + lane];

  for (int i = wid; i < N; i += nwaves) {
    const uint4* xr = (const uint4*)(x + (size_t)i * 64);
    float acc = 0.f;
#pragma unroll
    for (int q = 0; q < 8; ++q) {
      uint4 v = xr[q];
      acc += bflo(v.x) * Wc[8 * q + 0]; acc += bfhi(v.x) * Wc[8 * q + 1];
      acc += bflo(v.y) * Wc[8 * q + 2]; acc += bfhi(v.y) * Wc[8 * q + 3];
      acc += bflo(v.z) * Wc[8 * q + 4]; acc += bfhi(v.z) * Wc[8 * q + 5];
      acc += bflo(v.w) * Wc[8 * q + 6]; acc += bfhi(v.w) * Wc[8 * q + 7];
    }
    h[(size_t)i * 64 + lane] = f2bf(acc);
    float s1 = acc * as, s2 = acc * ad;
#pragma unroll
    for (int off = 32; off > 0; off >>= 1) {
      s1 += __shfl_xor(s1, off, 64);
      s2 += __shfl_xor(s2, off, 64);
    }
    if (lane == 0) { a_src[i] = s1; a_dst[i] = s2; }
  }
}

// ------------------------------------------------ per-dst: softmax + weighted sum + bias
__global__ void __launch_bounds__(256) gather_kernel(
    const u16* __restrict__ h, const float* __restrict__ a_src,
    const float* __restrict__ a_dst, const int* __restrict__ row_off,
    const int* __restrict__ csr_src, const float* __restrict__ pf,
    u16* __restrict__ xout, void* __restrict__ dout, int N, int last,
    const int* __restrict__ mode) {
  int lane = threadIdx.x & 63;
  int i = (int)((blockIdx.x * blockDim.x + threadIdx.x) >> 6);
  if (i >= N) return;
  int beg = row_off[i], end = row_off[i + 1];
  float adv = a_dst[i];
  float acc = 0.f, den = 0.f;
  for (int e = beg; e < end; ++e) {
    int s = csr_src[e];
    if ((unsigned)s >= (unsigned)N) continue;   // garbage-index guard
    float t = a_src[s] + adv;
    t = (t > 0.f) ? t : LRELU_SLOPE * t;
    t = fminf(fmaxf(t, -50.f), 50.f);           // exp can never produce inf/0-den
    float w = __expf(t);
    den += w;
    acc += w * bf2f(h[(size_t)s * 64 + lane]);
  }
  float b = pf[4224 + lane];
  float o = (den > 0.f) ? (acc / den + b) : b;
  size_t oi = (size_t)i * 64 + lane;
  if (last) {
    if (*mode) ((u16*)dout)[oi] = f2bf(o);
    else       ((float*)dout)[oi] = o;
  } else {
    xout[oi] = f2bf(o);
  }
}

// ------------------------------------------------ launcher
extern "C" void kernel_launch(void* const* d_in, const int* in_sizes, int n_in,
                              void* d_out, int out_size, void* d_ws, size_t ws_size,
                              hipStream_t stream) {
  const void* g     = d_in[0];
  const int*  edge  = (const int*)d_in[1];
  const void* Wp    = d_in[2];
  const void* attsp = d_in[3];
  const void* attdp = d_in[4];
  const void* biasp = d_in[5];

  const int D = 64;
  const int N = in_sizes[0] / D;
  const int E = in_sizes[1] / 2;
  const int* src = edge;
  const int* dst = edge + E;

  char* ws = (char*)d_ws;
  size_t off = 0;
  auto alloc = [&](size_t bytes) -> char* {
    char* p = ws + off;
    off += (bytes + 255) & ~size_t(255);
    return p;
  };
  u16*   x        = (u16*)alloc((size_t)N * D * sizeof(u16));    // 12.8 MB
  u16*   h        = (u16*)alloc((size_t)N * D * sizeof(u16));    // 12.8 MB
  float* pf       = (float*)alloc(4288 * sizeof(float));
  float* a_src    = (float*)alloc((size_t)N * sizeof(float));
  float* a_dst    = (float*)alloc((size_t)N * sizeof(float));
  int*   deg      = (int*)alloc((size_t)N * sizeof(int));
  int*   row_off  = (int*)alloc((size_t)(N + 1) * sizeof(int));
  int*   cursor   = (int*)alloc((size_t)N * sizeof(int));
  int*   csr_src  = (int*)alloc((size_t)E * sizeof(int));        // 4 MB
  int*   partials = (int*)alloc(1024 * sizeof(int));
  int*   mode     = (int*)alloc(256);
  // total ~= 32 MB

  detect_kernel<<<1, 256, 0, stream>>>((const u32*)g, 4096, mode);

  int n64 = N * D;
  conv_x_kernel<<<(n64 + 255) / 256, 256, 0, stream>>>(g, x, n64, mode);
  conv_params_kernel<<<17, 256, 0, stream>>>(Wp, attsp, attdp, biasp, pf, mode);

  hipMemsetAsync(deg, 0, (size_t)N * sizeof(int), stream);
  hist_kernel<<<(E + 255) / 256, 256, 0, stream>>>(dst, deg, E);
  int nblk = (N + 1023) / 1024;
  scan1_kernel<<<nblk, 1024, 0, stream>>>(deg, row_off, partials, N);
  scan2_kernel<<<1, 1024, 0, stream>>>(partials, nblk);
  scan3_kernel<<<nblk, 1024, 0, stream>>>(row_off, partials, N);
  hipMemcpyAsync(cursor, row_off, (size_t)N * sizeof(int), hipMemcpyDeviceToDevice, stream);
  scatter_kernel<<<(E + 255) / 256, 256, 0, stream>>>(src, dst, cursor, csr_src, E);

  for (int layer = 0; layer < 4; ++layer) {
    proj_kernel<<<1024, 256, 0, stream>>>(x, pf, h, a_src, a_dst, N);
    int last = (layer == 3) ? 1 : 0;
    gather_kernel<<<(N + 3) / 4, 256, 0, stream>>>(h, a_src, a_dst, row_off, csr_src, pf,
                                                   x, d_out, N, last, mode);
  }
}

// Round 3
// 562.704 us; speedup vs baseline: 1.4599x; 1.4599x over previous
//
#include <hip/hip_runtime.h>
#include <hip/hip_bf16.h>

typedef unsigned int u32;
typedef unsigned short u16;

#define LRELU_SLOPE 0.2f

__device__ inline float bfbits(u32 hi) { union { u32 i; float f; } v; v.i = hi; return v.f; }
__device__ inline float bflo(u32 w) { return bfbits(w << 16); }
__device__ inline float bfhi(u32 w) { return bfbits(w & 0xFFFF0000u); }
__device__ inline float bf2f(u16 s) { return bfbits(((u32)s) << 16); }
__device__ inline u16 f2bf(float f) {
  union { float f; u32 i; } v; v.f = f;
  u32 r = v.i + 0x7FFFu + ((v.i >> 16) & 1u); // round-to-nearest-even
  return (u16)(r >> 16);
}

// ------------------------------------------------ dtype sniff: bf16-packed vs f32
__global__ void detect_kernel(const u32* __restrict__ g, int nwords, int* __restrict__ mode) {
  __shared__ int cnt;
  if (threadIdx.x == 0) cnt = 0;
  __syncthreads();
  int c = 0;
  for (int i = threadIdx.x; i < nwords; i += blockDim.x) {
    u32 e = g[i] & 0x7F80u;
    if (e >= 0x3000u && e <= 0x4180u) c++;
  }
  atomicAdd(&cnt, c);
  __syncthreads();
  if (threadIdx.x == 0) *mode = (2 * cnt > nwords) ? 1 : 0; // 1 = inputs are bf16
}

// ------------------------------------------------ input normalization
__global__ void conv_x_kernel(const void* __restrict__ g, u16* __restrict__ x, int n,
                              const int* __restrict__ mode) {
  int i = blockIdx.x * blockDim.x + threadIdx.x;
  if (i >= n) return;
  if (*mode) x[i] = ((const u16*)g)[i];
  else       x[i] = f2bf(((const float*)g)[i]);
}

// pf layout: [0,4096) W row-major, [4096,4160) att_src, [4160,4224) att_dst, [4224,4288) bias
__global__ void conv_params_kernel(const void* __restrict__ W, const void* __restrict__ as,
                                   const void* __restrict__ ad, const void* __restrict__ bs,
                                   float* __restrict__ pf, const int* __restrict__ mode) {
  int i = blockIdx.x * blockDim.x + threadIdx.x;
  if (i >= 4288) return;
  const void* p; int j;
  if (i < 4096)      { p = W;  j = i; }
  else if (i < 4160) { p = as; j = i - 4096; }
  else if (i < 4224) { p = ad; j = i - 4160; }
  else               { p = bs; j = i - 4224; }
  pf[i] = (*mode) ? bf2f(((const u16*)p)[j]) : ((const float*)p)[j];
}

// ------------------------------------------------ CSR build
__global__ void hist_kernel(const int* __restrict__ dst, int* __restrict__ deg, int E) {
  int i = blockIdx.x * blockDim.x + threadIdx.x;
  if (i < E) atomicAdd(&deg[dst[i]], 1);
}

__global__ void scan1_kernel(const int* __restrict__ deg, int* __restrict__ row_off,
                             int* __restrict__ partials, int N) {
  __shared__ int smem[1024];
  int t = threadIdx.x;
  int idx = blockIdx.x * 1024 + t;
  int v = (idx < N) ? deg[idx] : 0;
  smem[t] = v;
  __syncthreads();
  for (int off = 1; off < 1024; off <<= 1) {
    int u = (t >= off) ? smem[t - off] : 0;
    __syncthreads();
    smem[t] += u;
    __syncthreads();
  }
  if (idx < N) row_off[idx + 1] = smem[t];
  if (t == 1023) partials[blockIdx.x] = smem[t];
}

__global__ void scan2_kernel(int* __restrict__ partials, int P) {
  __shared__ int smem[1024];
  int t = threadIdx.x;
  int v = (t < P) ? partials[t] : 0;
  smem[t] = v;
  __syncthreads();
  for (int off = 1; off < 1024; off <<= 1) {
    int u = (t >= off) ? smem[t - off] : 0;
    __syncthreads();
    smem[t] += u;
    __syncthreads();
  }
  if (t < P) partials[t] = smem[t];
}

__global__ void scan3_kernel(int* __restrict__ row_off, const int* __restrict__ partials, int N) {
  int b = blockIdx.x;
  int idx = b * 1024 + threadIdx.x;
  if (b > 0 && idx < N) row_off[idx + 1] += partials[b - 1];
  if (idx == 0) row_off[0] = 0;
}

__global__ void scatter_kernel(const int* __restrict__ src, const int* __restrict__ dst,
                               int* __restrict__ cursor, int* __restrict__ csr_src, int E) {
  int i = blockIdx.x * blockDim.x + threadIdx.x;
  if (i < E) {
    int p = atomicAdd(&cursor[dst[i]], 1);
    csr_src[p] = src[i];
  }
}

// ------------------------------------------------ h = x@W, a_src = h.att_s, a_dst = h.att_d
__global__ void __launch_bounds__(256) proj_kernel(
    const u16* __restrict__ x, const float* __restrict__ pf,
    u16* __restrict__ h, float* __restrict__ a_src, float* __restrict__ a_dst, int N) {
  int lane = threadIdx.x & 63;
  int wid = (int)((blockIdx.x * blockDim.x + threadIdx.x) >> 6);
  int nwaves = (int)((gridDim.x * blockDim.x) >> 6);

  float Wc[64];
#pragma unroll
  for (int k = 0; k < 64; ++k) Wc[k] = pf[k * 64 + lane];
  float as = pf[4096 + lane];
  float ad = pf[4160 + lane];

  for (int i = wid; i < N; i += nwaves) {
    const uint4* xr = (const uint4*)(x + (size_t)i * 64);
    float a0 = 0.f, a1 = 0.f, a2 = 0.f, a3 = 0.f;  // 4 chains for ILP
#pragma unroll
    for (int q = 0; q < 8; ++q) {
      uint4 v = xr[q];
      a0 += bflo(v.x) * Wc[8 * q + 0]; a1 += bfhi(v.x) * Wc[8 * q + 1];
      a2 += bflo(v.y) * Wc[8 * q + 2]; a3 += bfhi(v.y) * Wc[8 * q + 3];
      a0 += bflo(v.z) * Wc[8 * q + 4]; a1 += bfhi(v.z) * Wc[8 * q + 5];
      a2 += bflo(v.w) * Wc[8 * q + 6]; a3 += bfhi(v.w) * Wc[8 * q + 7];
    }
    float acc = (a0 + a1) + (a2 + a3);
    h[(size_t)i * 64 + lane] = f2bf(acc);
    float s1 = acc * as, s2 = acc * ad;
#pragma unroll
    for (int off = 32; off > 0; off >>= 1) {
      s1 += __shfl_xor(s1, off, 64);
      s2 += __shfl_xor(s2, off, 64);
    }
    if (lane == 0) { a_src[i] = s1; a_dst[i] = s2; }
  }
}

// ------------------------------------------------ per-dst: softmax + weighted sum + bias
// One wave per dst node. 8 edge-groups x 8 feature-lanes: one dwordx4 load
// instruction covers 8 edges' 128B h-rows (1KB in flight) -> 8x MLP vs scalar loop.
__global__ void __launch_bounds__(256) gather_kernel(
    const u16* __restrict__ h, const float* __restrict__ a_src,
    const float* __restrict__ a_dst, const int* __restrict__ row_off,
    const int* __restrict__ csr_src, const float* __restrict__ pf,
    u16* __restrict__ xout, void* __restrict__ dout, int N, int last,
    const int* __restrict__ mode) {
  int lane = threadIdx.x & 63;
  int eg = lane >> 3;   // edge group 0..7
  int fg = lane & 7;    // feature octet 0..7
  int i = (int)((blockIdx.x * blockDim.x + threadIdx.x) >> 6);
  if (i >= N) return;   // i is wave-uniform: whole wave exits together

  int beg = row_off[i], end = row_off[i + 1];
  float adv = a_dst[i];
  float acc[8] = {0.f, 0.f, 0.f, 0.f, 0.f, 0.f, 0.f, 0.f};
  float den = 0.f;

  for (int e0 = beg; e0 < end; e0 += 8) {
    int e = e0 + eg;
    bool valid = (e < end);
    int s = valid ? csr_src[e] : 0;
    float t = a_src[s] + adv;
    t = (t > 0.f) ? t : LRELU_SLOPE * t;
    t = fminf(fmaxf(t, -60.f), 60.f);
    float w = valid ? __expf(t) : 0.f;
    den += w;
    uint4 hv = ((const uint4*)(h + (size_t)s * 64))[fg];
    acc[0] += w * bflo(hv.x); acc[1] += w * bfhi(hv.x);
    acc[2] += w * bflo(hv.y); acc[3] += w * bfhi(hv.y);
    acc[4] += w * bflo(hv.z); acc[5] += w * bfhi(hv.z);
    acc[6] += w * bflo(hv.w); acc[7] += w * bfhi(hv.w);
  }

  // reduce across the 8 edge groups (lane bits 3..5)
#pragma unroll
  for (int m = 8; m <= 32; m <<= 1) {
    den += __shfl_xor(den, m, 64);
#pragma unroll
    for (int j = 0; j < 8; ++j) acc[j] += __shfl_xor(acc[j], m, 64);
  }
  float inv = (den > 0.f) ? 1.f / den : 0.f;

  if (*mode || !last) {
    // bf16 row store: 8 lanes x uint4 = 128B coalesced
    if (eg == 0) {
      u32 o[4];
#pragma unroll
      for (int j = 0; j < 4; ++j) {
        float f0 = acc[2 * j]     * inv + pf[4224 + 8 * fg + 2 * j];
        float f1 = acc[2 * j + 1] * inv + pf[4224 + 8 * fg + 2 * j + 1];
        o[j] = (u32)f2bf(f0) | ((u32)f2bf(f1) << 16);
      }
      u16* base = last ? (u16*)dout : xout;
      *(uint4*)(base + (size_t)i * 64 + fg * 8) = make_uint4(o[0], o[1], o[2], o[3]);
    }
  } else {
    // f32 final store: broadcast via bpermute, per-lane f32 write (256B coalesced)
    float o[8];
#pragma unroll
    for (int j = 0; j < 8; ++j)
      o[j] = acc[j] * inv + pf[4224 + 8 * fg + j];
    int srcl = lane >> 3;  // lane holding this lane's feature octet (eg==0 copy)
    float t0, t1, t2, t3;
#pragma unroll
    for (int j = 0; j < 8; ++j) {
      float v = __shfl(o[j], srcl, 64);
      if (j == 0) t0 = v;
      else {
        int sel = lane & 7;
        t0 = (sel == j) ? v : t0;
      }
    }
    (void)t1; (void)t2; (void)t3;
    ((float*)dout)[(size_t)i * 64 + lane] = t0;
  }
}

// ------------------------------------------------ launcher
extern "C" void kernel_launch(void* const* d_in, const int* in_sizes, int n_in,
                              void* d_out, int out_size, void* d_ws, size_t ws_size,
                              hipStream_t stream) {
  const void* g     = d_in[0];
  const int*  edge  = (const int*)d_in[1];
  const void* Wp    = d_in[2];
  const void* attsp = d_in[3];
  const void* attdp = d_in[4];
  const void* biasp = d_in[5];

  const int D = 64;
  const int N = in_sizes[0] / D;
  const int E = in_sizes[1] / 2;
  const int* src = edge;
  const int* dst = edge + E;

  char* ws = (char*)d_ws;
  size_t off = 0;
  auto alloc = [&](size_t bytes) -> char* {
    char* p = ws + off;
    off += (bytes + 255) & ~size_t(255);
    return p;
  };
  u16*   x        = (u16*)alloc((size_t)N * D * sizeof(u16));    // 12.8 MB
  u16*   h        = (u16*)alloc((size_t)N * D * sizeof(u16));    // 12.8 MB
  float* pf       = (float*)alloc(4288 * sizeof(float));
  float* a_src    = (float*)alloc((size_t)N * sizeof(float));
  float* a_dst    = (float*)alloc((size_t)N * sizeof(float));
  int*   deg      = (int*)alloc((size_t)N * sizeof(int));
  int*   row_off  = (int*)alloc((size_t)(N + 1) * sizeof(int));
  int*   cursor   = (int*)alloc((size_t)N * sizeof(int));
  int*   csr_src  = (int*)alloc((size_t)E * sizeof(int));        // 4 MB
  int*   partials = (int*)alloc(1024 * sizeof(int));
  int*   mode     = (int*)alloc(256);

  detect_kernel<<<1, 256, 0, stream>>>((const u32*)g, 4096, mode);

  int n64 = N * D;
  conv_x_kernel<<<(n64 + 255) / 256, 256, 0, stream>>>(g, x, n64, mode);
  conv_params_kernel<<<17, 256, 0, stream>>>(Wp, attsp, attdp, biasp, pf, mode);

  hipMemsetAsync(deg, 0, (size_t)N * sizeof(int), stream);
  hist_kernel<<<(E + 255) / 256, 256, 0, stream>>>(dst, deg, E);
  int nblk = (N + 1023) / 1024;
  scan1_kernel<<<nblk, 1024, 0, stream>>>(deg, row_off, partials, N);
  scan2_kernel<<<1, 1024, 0, stream>>>(partials, nblk);
  scan3_kernel<<<nblk, 1024, 0, stream>>>(row_off, partials, N);
  hipMemcpyAsync(cursor, row_off, (size_t)N * sizeof(int), hipMemcpyDeviceToDevice, stream);
  scatter_kernel<<<(E + 255) / 256, 256, 0, stream>>>(src, dst, cursor, csr_src, E);

  for (int layer = 0; layer < 4; ++layer) {
    proj_kernel<<<1024, 256, 0, stream>>>(x, pf, h, a_src, a_dst, N);
    int last = (layer == 3) ? 1 : 0;
    gather_kernel<<<(N + 3) / 4, 256, 0, stream>>>(h, a_src, a_dst, row_off, csr_src, pf,
                                                   x, d_out, N, last, mode);
  }
}

// Round 4
// 545.514 us; speedup vs baseline: 1.5060x; 1.0315x over previous
//
#include <hip/hip_runtime.h>
#include <hip/hip_bf16.h>

typedef unsigned int u32;
typedef unsigned short u16;

#define LRELU_SLOPE 0.2f

__device__ inline float bfbits(u32 hi) { union { u32 i; float f; } v; v.i = hi; return v.f; }
__device__ inline float bflo(u32 w) { return bfbits(w << 16); }
__device__ inline float bfhi(u32 w) { return bfbits(w & 0xFFFF0000u); }
__device__ inline float bf2f(u16 s) { return bfbits(((u32)s) << 16); }
__device__ inline u16 f2bf(float f) {
  union { float f; u32 i; } v; v.f = f;
  u32 r = v.i + 0x7FFFu + ((v.i >> 16) & 1u); // round-to-nearest-even
  return (u16)(r >> 16);
}

// ------------------------------------------------ dtype sniff: bf16-packed vs f32
__global__ void detect_kernel(const u32* __restrict__ g, int nwords, int* __restrict__ mode) {
  __shared__ int cnt;
  if (threadIdx.x == 0) cnt = 0;
  __syncthreads();
  int c = 0;
  for (int i = threadIdx.x; i < nwords; i += blockDim.x) {
    u32 e = g[i] & 0x7F80u;
    if (e >= 0x3000u && e <= 0x4180u) c++;
  }
  atomicAdd(&cnt, c);
  __syncthreads();
  if (threadIdx.x == 0) *mode = (2 * cnt > nwords) ? 1 : 0; // 1 = inputs are bf16
}

// ------------------------------------------------ input normalization
__global__ void conv_x_kernel(const void* __restrict__ g, u16* __restrict__ x, int n,
                              const int* __restrict__ mode) {
  int i = blockIdx.x * blockDim.x + threadIdx.x;
  if (i >= n) return;
  if (*mode) x[i] = ((const u16*)g)[i];
  else       x[i] = f2bf(((const float*)g)[i]);
}

// pf layout: [0,4096) W row-major, [4096,4160) att_src, [4160,4224) att_dst, [4224,4288) bias
__global__ void conv_params_kernel(const void* __restrict__ W, const void* __restrict__ as,
                                   const void* __restrict__ ad, const void* __restrict__ bs,
                                   float* __restrict__ pf, const int* __restrict__ mode) {
  int i = blockIdx.x * blockDim.x + threadIdx.x;
  if (i >= 4288) return;
  const void* p; int j;
  if (i < 4096)      { p = W;  j = i; }
  else if (i < 4160) { p = as; j = i - 4096; }
  else if (i < 4224) { p = ad; j = i - 4160; }
  else               { p = bs; j = i - 4224; }
  pf[i] = (*mode) ? bf2f(((const u16*)p)[j]) : ((const float*)p)[j];
}

// ------------------------------------------------ CSR build, XCD-partitioned
// xcd = blockIdx&7 (round-robin heuristic). Each XCD scans the whole edge list
// but only touches deg/cursor/csr lines in its own dst range -> no cross-XCD
// L2 line ping-pong on the scattered atomics/stores.
__global__ void hist_part_kernel(const int* __restrict__ dst, int* __restrict__ deg,
                                 int E, int nper) {
  int xcd = blockIdx.x & 7;
  int vb = blockIdx.x >> 3;
  int nvb = gridDim.x >> 3;
  int lo = xcd * nper, hi = lo + nper;
  for (int i = vb * blockDim.x + threadIdx.x; i < E; i += nvb * blockDim.x) {
    int d = dst[i];
    if (d >= lo && d < hi) atomicAdd(&deg[d], 1);
  }
}

__global__ void scatter_part_kernel(const int* __restrict__ src, const int* __restrict__ dst,
                                    int* __restrict__ cursor, int* __restrict__ csr_src,
                                    int E, int nper) {
  int xcd = blockIdx.x & 7;
  int vb = blockIdx.x >> 3;
  int nvb = gridDim.x >> 3;
  int lo = xcd * nper, hi = lo + nper;
  for (int i = vb * blockDim.x + threadIdx.x; i < E; i += nvb * blockDim.x) {
    int d = dst[i];
    if (d >= lo && d < hi) {
      int p = atomicAdd(&cursor[d], 1);
      csr_src[p] = src[i];
    }
  }
}

__global__ void scan1_kernel(const int* __restrict__ deg, int* __restrict__ row_off,
                             int* __restrict__ partials, int N) {
  __shared__ int smem[1024];
  int t = threadIdx.x;
  int idx = blockIdx.x * 1024 + t;
  int v = (idx < N) ? deg[idx] : 0;
  smem[t] = v;
  __syncthreads();
  for (int off = 1; off < 1024; off <<= 1) {
    int u = (t >= off) ? smem[t - off] : 0;
    __syncthreads();
    smem[t] += u;
    __syncthreads();
  }
  if (idx < N) row_off[idx + 1] = smem[t];
  if (t == 1023) partials[blockIdx.x] = smem[t];
}

__global__ void scan2_kernel(int* __restrict__ partials, int P) {
  __shared__ int smem[1024];
  int t = threadIdx.x;
  int v = (t < P) ? partials[t] : 0;
  smem[t] = v;
  __syncthreads();
  for (int off = 1; off < 1024; off <<= 1) {
    int u = (t >= off) ? smem[t - off] : 0;
    __syncthreads();
    smem[t] += u;
    __syncthreads();
  }
  if (t < P) partials[t] = smem[t];
}

__global__ void scan3_kernel(int* __restrict__ row_off, const int* __restrict__ partials, int N) {
  int b = blockIdx.x;
  int idx = b * 1024 + threadIdx.x;
  if (b > 0 && idx < N) row_off[idx + 1] += partials[b - 1];
  if (idx == 0) row_off[0] = 0;
}

// ------------------------------------------------ h = x@W, a_src = h.att_s, a_dst = h.att_d
__global__ void __launch_bounds__(256) proj_kernel(
    const u16* __restrict__ x, const float* __restrict__ pf,
    u16* __restrict__ h, float* __restrict__ a_src, float* __restrict__ a_dst, int N) {
  int lane = threadIdx.x & 63;
  int wid = (int)((blockIdx.x * blockDim.x + threadIdx.x) >> 6);
  int nwaves = (int)((gridDim.x * blockDim.x) >> 6);

  float Wc[64];
#pragma unroll
  for (int k = 0; k < 64; ++k) Wc[k] = pf[k * 64 + lane];
  float as = pf[4096 + lane];
  float ad = pf[4160 + lane];

  for (int i = wid; i < N; i += nwaves) {
    const uint4* xr = (const uint4*)(x + (size_t)i * 64);
    float a0 = 0.f, a1 = 0.f, a2 = 0.f, a3 = 0.f;  // 4 chains for ILP
#pragma unroll
    for (int q = 0; q < 8; ++q) {
      uint4 v = xr[q];
      a0 += bflo(v.x) * Wc[8 * q + 0]; a1 += bfhi(v.x) * Wc[8 * q + 1];
      a2 += bflo(v.y) * Wc[8 * q + 2]; a3 += bfhi(v.y) * Wc[8 * q + 3];
      a0 += bflo(v.z) * Wc[8 * q + 4]; a1 += bfhi(v.z) * Wc[8 * q + 5];
      a2 += bflo(v.w) * Wc[8 * q + 6]; a3 += bfhi(v.w) * Wc[8 * q + 7];
    }
    float acc = (a0 + a1) + (a2 + a3);
    h[(size_t)i * 64 + lane] = f2bf(acc);
    float s1 = acc * as, s2 = acc * ad;
#pragma unroll
    for (int off = 32; off > 0; off >>= 1) {
      s1 += __shfl_xor(s1, off, 64);
      s2 += __shfl_xor(s2, off, 64);
    }
    if (lane == 0) { a_src[i] = s1; a_dst[i] = s2; }
  }
}

// ------------------------------------------------ per-dst: softmax + weighted sum + bias
// One wave per dst node. 8 edge-groups x 8 feature-lanes.
__global__ void __launch_bounds__(256) gather_kernel(
    const u16* __restrict__ h, const float* __restrict__ a_src,
    const float* __restrict__ a_dst, const int* __restrict__ row_off,
    const int* __restrict__ csr_src, const float* __restrict__ pf,
    u16* __restrict__ xout, void* __restrict__ dout, int N, int last,
    const int* __restrict__ mode) {
  int lane = threadIdx.x & 63;
  int eg = lane >> 3;   // edge group 0..7
  int fg = lane & 7;    // feature octet 0..7
  int i = (int)((blockIdx.x * blockDim.x + threadIdx.x) >> 6);
  if (i >= N) return;   // i is wave-uniform: whole wave exits together

  int beg = row_off[i], end = row_off[i + 1];
  float adv = a_dst[i];
  float acc[8] = {0.f, 0.f, 0.f, 0.f, 0.f, 0.f, 0.f, 0.f};
  float den = 0.f;

  for (int e0 = beg; e0 < end; e0 += 8) {
    int e = e0 + eg;
    bool valid = (e < end);
    int s = valid ? csr_src[e] : 0;
    float t = a_src[s] + adv;
    t = (t > 0.f) ? t : LRELU_SLOPE * t;
    t = fminf(fmaxf(t, -60.f), 60.f);
    float w = valid ? __expf(t) : 0.f;
    den += w;
    uint4 hv = ((const uint4*)(h + (size_t)s * 64))[fg];
    acc[0] += w * bflo(hv.x); acc[1] += w * bfhi(hv.x);
    acc[2] += w * bflo(hv.y); acc[3] += w * bfhi(hv.y);
    acc[4] += w * bflo(hv.z); acc[5] += w * bfhi(hv.z);
    acc[6] += w * bflo(hv.w); acc[7] += w * bfhi(hv.w);
  }

  // reduce across the 8 edge groups (lane bits 3..5)
#pragma unroll
  for (int m = 8; m <= 32; m <<= 1) {
    den += __shfl_xor(den, m, 64);
#pragma unroll
    for (int j = 0; j < 8; ++j) acc[j] += __shfl_xor(acc[j], m, 64);
  }
  float inv = (den > 0.f) ? 1.f / den : 0.f;

  if (*mode || !last) {
    // bf16 row store: 8 lanes x uint4 = 128B coalesced
    if (eg == 0) {
      u32 o[4];
#pragma unroll
      for (int j = 0; j < 4; ++j) {
        float f0 = acc[2 * j]     * inv + pf[4224 + 8 * fg + 2 * j];
        float f1 = acc[2 * j + 1] * inv + pf[4224 + 8 * fg + 2 * j + 1];
        o[j] = (u32)f2bf(f0) | ((u32)f2bf(f1) << 16);
      }
      u16* base = last ? (u16*)dout : xout;
      *(uint4*)(base + (size_t)i * 64 + fg * 8) = make_uint4(o[0], o[1], o[2], o[3]);
    }
  } else {
    // f32 final store: broadcast from eg==0 lanes, per-lane f32 write
    float o[8];
#pragma unroll
    for (int j = 0; j < 8; ++j)
      o[j] = acc[j] * inv + pf[4224 + 8 * fg + j];
    int srcl = lane >> 3;  // lane holding this lane's feature octet (eg==0 copy)
    float t0 = 0.f;
#pragma unroll
    for (int j = 0; j < 8; ++j) {
      float v = __shfl(o[j], srcl, 64);
      t0 = ((lane & 7) == j) ? v : t0;
    }
    ((float*)dout)[(size_t)i * 64 + lane] = t0;
  }
}

// ------------------------------------------------ launcher
extern "C" void kernel_launch(void* const* d_in, const int* in_sizes, int n_in,
                              void* d_out, int out_size, void* d_ws, size_t ws_size,
                              hipStream_t stream) {
  const void* g     = d_in[0];
  const int*  edge  = (const int*)d_in[1];
  const void* Wp    = d_in[2];
  const void* attsp = d_in[3];
  const void* attdp = d_in[4];
  const void* biasp = d_in[5];

  const int D = 64;
  const int N = in_sizes[0] / D;
  const int E = in_sizes[1] / 2;
  const int* src = edge;
  const int* dst = edge + E;

  char* ws = (char*)d_ws;
  size_t off = 0;
  auto alloc = [&](size_t bytes) -> char* {
    char* p = ws + off;
    off += (bytes + 255) & ~size_t(255);
    return p;
  };
  u16*   x        = (u16*)alloc((size_t)N * D * sizeof(u16));    // 12.8 MB
  u16*   h        = (u16*)alloc((size_t)N * D * sizeof(u16));    // 12.8 MB
  float* pf       = (float*)alloc(4288 * sizeof(float));
  float* a_src    = (float*)alloc((size_t)N * sizeof(float));
  float* a_dst    = (float*)alloc((size_t)N * sizeof(float));
  int*   deg      = (int*)alloc((size_t)N * sizeof(int));
  int*   row_off  = (int*)alloc((size_t)(N + 1) * sizeof(int));
  int*   cursor   = (int*)alloc((size_t)N * sizeof(int));
  int*   csr_src  = (int*)alloc((size_t)E * sizeof(int));        // 4 MB
  int*   partials = (int*)alloc(1024 * sizeof(int));
  int*   mode     = (int*)alloc(256);

  detect_kernel<<<1, 256, 0, stream>>>((const u32*)g, 4096, mode);

  int n64 = N * D;
  conv_x_kernel<<<(n64 + 255) / 256, 256, 0, stream>>>(g, x, n64, mode);
  conv_params_kernel<<<17, 256, 0, stream>>>(Wp, attsp, attdp, biasp, pf, mode);

  int nper = (N + 7) / 8;  // dst ids per XCD bucket
  hipMemsetAsync(deg, 0, (size_t)N * sizeof(int), stream);
  hist_part_kernel<<<1024, 256, 0, stream>>>(dst, deg, E, nper);
  int nblk = (N + 1023) / 1024;
  scan1_kernel<<<nblk, 1024, 0, stream>>>(deg, row_off, partials, N);
  scan2_kernel<<<1, 1024, 0, stream>>>(partials, nblk);
  scan3_kernel<<<nblk, 1024, 0, stream>>>(row_off, partials, N);
  hipMemcpyAsync(cursor, row_off, (size_t)N * sizeof(int), hipMemcpyDeviceToDevice, stream);
  scatter_part_kernel<<<1024, 256, 0, stream>>>(src, dst, cursor, csr_src, E, nper);

  for (int layer = 0; layer < 4; ++layer) {
    proj_kernel<<<1024, 256, 0, stream>>>(x, pf, h, a_src, a_dst, N);
    int last = (layer == 3) ? 1 : 0;
    gather_kernel<<<(N + 3) / 4, 256, 0, stream>>>(h, a_src, a_dst, row_off, csr_src, pf,
                                                   x, d_out, N, last, mode);
  }
}

// Round 5
// 423.226 us; speedup vs baseline: 1.9411x; 1.2889x over previous
//
#include <hip/hip_runtime.h>
#include <hip/hip_bf16.h>

typedef unsigned int u32;
typedef unsigned short u16;
typedef __attribute__((ext_vector_type(8))) short short8;   // 8 bf16 = 4 VGPRs
typedef __attribute__((ext_vector_type(4))) float f32x4;

#define LRELU_SLOPE 0.2f

__device__ inline float bfbits(u32 hi) { union { u32 i; float f; } v; v.i = hi; return v.f; }
__device__ inline float bflo(u32 w) { return bfbits(w << 16); }
__device__ inline float bfhi(u32 w) { return bfbits(w & 0xFFFF0000u); }
__device__ inline float bf2f(u16 s) { return bfbits(((u32)s) << 16); }
__device__ inline u16 f2bf(float f) {
  union { float f; u32 i; } v; v.f = f;
  u32 r = v.i + 0x7FFFu + ((v.i >> 16) & 1u); // round-to-nearest-even
  return (u16)(r >> 16);
}

// ------------------------------------------------ dtype sniff: bf16-packed vs f32
__global__ void detect_kernel(const u32* __restrict__ g, int nwords, int* __restrict__ mode) {
  __shared__ int cnt;
  if (threadIdx.x == 0) cnt = 0;
  __syncthreads();
  int c = 0;
  for (int i = threadIdx.x; i < nwords; i += blockDim.x) {
    u32 e = g[i] & 0x7F80u;
    if (e >= 0x3000u && e <= 0x4180u) c++;
  }
  atomicAdd(&cnt, c);
  __syncthreads();
  if (threadIdx.x == 0) *mode = (2 * cnt > nwords) ? 1 : 0; // 1 = inputs are bf16
}

// ------------------------------------------------ input normalization
__global__ void conv_x_kernel(const void* __restrict__ g, u16* __restrict__ x, int n,
                              const int* __restrict__ mode) {
  int i = blockIdx.x * blockDim.x + threadIdx.x;
  if (i >= n) return;
  if (*mode) x[i] = ((const u16*)g)[i];
  else       x[i] = f2bf(((const float*)g)[i]);
}

// pf layout: [0,4096) W row-major, [4096,4160) att_src, [4160,4224) att_dst, [4224,4288) bias
__global__ void conv_params_kernel(const void* __restrict__ W, const void* __restrict__ as,
                                   const void* __restrict__ ad, const void* __restrict__ bs,
                                   float* __restrict__ pf, const int* __restrict__ mode) {
  int i = blockIdx.x * blockDim.x + threadIdx.x;
  if (i >= 4288) return;
  const void* p; int j;
  if (i < 4096)      { p = W;  j = i; }
  else if (i < 4160) { p = as; j = i - 4096; }
  else if (i < 4224) { p = ad; j = i - 4160; }
  else               { p = bs; j = i - 4224; }
  pf[i] = (*mode) ? bf2f(((const u16*)p)[j]) : ((const float*)p)[j];
}

// W pre-packed into per-lane MFMA B-fragment order:
// frag f = c*2 + t (col-tile c, K-step t); element (f, lane, j) = W[32t+8*(lane>>4)+j][16c+(lane&15)]
__global__ void wfrag_build_kernel(const float* __restrict__ pf, u16* __restrict__ wfrag) {
  int i = blockIdx.x * blockDim.x + threadIdx.x;
  if (i >= 4096) return;
  int f = i >> 9, lane = (i >> 3) & 63, j = i & 7;
  int c = f >> 1, t = f & 1;
  int k = 32 * t + 8 * (lane >> 4) + j;
  int n = 16 * c + (lane & 15);
  wfrag[i] = f2bf(pf[k * 64 + n]);
}

// ------------------------------------------------ CSR build, XCD-partitioned
__global__ void hist_part_kernel(const int* __restrict__ dst, int* __restrict__ deg,
                                 int E, int nper) {
  int xcd = blockIdx.x & 7;
  int vb = blockIdx.x >> 3;
  int nvb = gridDim.x >> 3;
  int lo = xcd * nper, hi = lo + nper;
  for (int i = vb * blockDim.x + threadIdx.x; i < E; i += nvb * blockDim.x) {
    int d = dst[i];
    if (d >= lo && d < hi) atomicAdd(&deg[d], 1);
  }
}

__global__ void scatter_part_kernel(const int* __restrict__ src, const int* __restrict__ dst,
                                    int* __restrict__ cursor, int* __restrict__ csr_src,
                                    int E, int nper) {
  int xcd = blockIdx.x & 7;
  int vb = blockIdx.x >> 3;
  int nvb = gridDim.x >> 3;
  int lo = xcd * nper, hi = lo + nper;
  for (int i = vb * blockDim.x + threadIdx.x; i < E; i += nvb * blockDim.x) {
    int d = dst[i];
    if (d >= lo && d < hi) {
      int p = atomicAdd(&cursor[d], 1);
      csr_src[p] = src[i];
    }
  }
}

__global__ void scan1_kernel(const int* __restrict__ deg, int* __restrict__ row_off,
                             int* __restrict__ partials, int N) {
  __shared__ int smem[1024];
  int t = threadIdx.x;
  int idx = blockIdx.x * 1024 + t;
  int v = (idx < N) ? deg[idx] : 0;
  smem[t] = v;
  __syncthreads();
  for (int off = 1; off < 1024; off <<= 1) {
    int u = (t >= off) ? smem[t - off] : 0;
    __syncthreads();
    smem[t] += u;
    __syncthreads();
  }
  if (idx < N) row_off[idx + 1] = smem[t];
  if (t == 1023) partials[blockIdx.x] = smem[t];
}

__global__ void scan2_kernel(int* __restrict__ partials, int P) {
  __shared__ int smem[1024];
  int t = threadIdx.x;
  int v = (t < P) ? partials[t] : 0;
  smem[t] = v;
  __syncthreads();
  for (int off = 1; off < 1024; off <<= 1) {
    int u = (t >= off) ? smem[t - off] : 0;
    __syncthreads();
    smem[t] += u;
    __syncthreads();
  }
  if (t < P) partials[t] = smem[t];
}

__global__ void scan3_kernel(int* __restrict__ row_off, const int* __restrict__ partials, int N) {
  int b = blockIdx.x;
  int idx = b * 1024 + threadIdx.x;
  if (b > 0 && idx < N) row_off[idx + 1] += partials[b - 1];
  if (idx == 0) row_off[0] = 0;
}

// ------------------------------------------------ h = x@W via MFMA, fused a_src/a_dst
// One wave per 16-row tile. A[m=lane&15][k=quad*8+j] (contiguous 16B load);
// B pre-packed in wfrag; D: col=lane&15, row=quad*4+reg (m89-verified).
__global__ void __launch_bounds__(256) proj_mfma_kernel(
    const u16* __restrict__ x, const u16* __restrict__ wfrag, const float* __restrict__ pf,
    u16* __restrict__ h, float* __restrict__ a_src, float* __restrict__ a_dst, int N) {
  int lane = threadIdx.x & 63;
  int quad = lane >> 4, m = lane & 15;
  int wtile = (int)((blockIdx.x * (size_t)blockDim.x + threadIdx.x) >> 6);
  int ntiles = (N + 15) >> 4;
  int nwaves = (int)((gridDim.x * (size_t)blockDim.x) >> 6);

  short8 bfrag[8];
#pragma unroll
  for (int f = 0; f < 8; ++f)
    bfrag[f] = *(const short8*)(wfrag + f * 512 + lane * 8);
  float asv[4], adv[4];
#pragma unroll
  for (int c = 0; c < 4; ++c) {
    asv[c] = pf[4096 + 16 * c + m];
    adv[c] = pf[4160 + 16 * c + m];
  }

  for (int tile = wtile; tile < ntiles; tile += nwaves) {
    int row0 = tile << 4;
    int rl = row0 + m; if (rl > N - 1) rl = N - 1;
    const u16* xr = x + (size_t)rl * 64 + 8 * quad;
    short8 a0 = *(const short8*)(xr);
    short8 a1 = *(const short8*)(xr + 32);

    f32x4 acc[4];
#pragma unroll
    for (int c = 0; c < 4; ++c) {
      f32x4 z = {0.f, 0.f, 0.f, 0.f};
      z = __builtin_amdgcn_mfma_f32_16x16x32_bf16(a0, bfrag[2 * c + 0], z, 0, 0, 0);
      z = __builtin_amdgcn_mfma_f32_16x16x32_bf16(a1, bfrag[2 * c + 1], z, 0, 0, 0);
      acc[c] = z;
    }

#pragma unroll
    for (int r = 0; r < 4; ++r) {
      int row = row0 + 4 * quad + r;
      float v0 = acc[0][r], v1 = acc[1][r], v2 = acc[2][r], v3 = acc[3][r];
      if (row < N) {
        u16* hr = h + (size_t)row * 64 + m;
        hr[0]  = f2bf(v0);
        hr[16] = f2bf(v1);
        hr[32] = f2bf(v2);
        hr[48] = f2bf(v3);
      }
      float s1 = v0 * asv[0] + v1 * asv[1] + v2 * asv[2] + v3 * asv[3];
      float s2 = v0 * adv[0] + v1 * adv[1] + v2 * adv[2] + v3 * adv[3];
#pragma unroll
      for (int msk = 1; msk <= 8; msk <<= 1) {
        s1 += __shfl_xor(s1, msk, 64);
        s2 += __shfl_xor(s2, msk, 64);
      }
      if (m == 0 && row < N) { a_src[row] = s1; a_dst[row] = s2; }
    }
  }
}

// ------------------------------------------------ per-dst: softmax + weighted sum + bias
// One wave per dst node. 8 edge-groups x 8 feature-lanes.
__global__ void __launch_bounds__(256) gather_kernel(
    const u16* __restrict__ h, const float* __restrict__ a_src,
    const float* __restrict__ a_dst, const int* __restrict__ row_off,
    const int* __restrict__ csr_src, const float* __restrict__ pf,
    u16* __restrict__ xout, void* __restrict__ dout, int N, int last,
    const int* __restrict__ mode) {
  int lane = threadIdx.x & 63;
  int eg = lane >> 3;   // edge group 0..7
  int fg = lane & 7;    // feature octet 0..7
  int i = (int)((blockIdx.x * blockDim.x + threadIdx.x) >> 6);
  if (i >= N) return;   // i is wave-uniform: whole wave exits together

  int beg = row_off[i], end = row_off[i + 1];
  float adv = a_dst[i];
  float acc[8] = {0.f, 0.f, 0.f, 0.f, 0.f, 0.f, 0.f, 0.f};
  float den = 0.f;

  for (int e0 = beg; e0 < end; e0 += 8) {
    int e = e0 + eg;
    bool valid = (e < end);
    int s = valid ? csr_src[e] : 0;
    float t = a_src[s] + adv;
    t = (t > 0.f) ? t : LRELU_SLOPE * t;
    t = fminf(fmaxf(t, -60.f), 60.f);
    float w = valid ? __expf(t) : 0.f;
    den += w;
    uint4 hv = ((const uint4*)(h + (size_t)s * 64))[fg];
    acc[0] += w * bflo(hv.x); acc[1] += w * bfhi(hv.x);
    acc[2] += w * bflo(hv.y); acc[3] += w * bfhi(hv.y);
    acc[4] += w * bflo(hv.z); acc[5] += w * bfhi(hv.z);
    acc[6] += w * bflo(hv.w); acc[7] += w * bfhi(hv.w);
  }

#pragma unroll
  for (int msk = 8; msk <= 32; msk <<= 1) {
    den += __shfl_xor(den, msk, 64);
#pragma unroll
    for (int j = 0; j < 8; ++j) acc[j] += __shfl_xor(acc[j], msk, 64);
  }
  float inv = (den > 0.f) ? 1.f / den : 0.f;

  if (*mode || !last) {
    if (eg == 0) {
      u32 o[4];
#pragma unroll
      for (int j = 0; j < 4; ++j) {
        float f0 = acc[2 * j]     * inv + pf[4224 + 8 * fg + 2 * j];
        float f1 = acc[2 * j + 1] * inv + pf[4224 + 8 * fg + 2 * j + 1];
        o[j] = (u32)f2bf(f0) | ((u32)f2bf(f1) << 16);
      }
      u16* base = last ? (u16*)dout : xout;
      *(uint4*)(base + (size_t)i * 64 + fg * 8) = make_uint4(o[0], o[1], o[2], o[3]);
    }
  } else {
    float o[8];
#pragma unroll
    for (int j = 0; j < 8; ++j)
      o[j] = acc[j] * inv + pf[4224 + 8 * fg + j];
    int srcl = lane >> 3;
    float t0 = 0.f;
#pragma unroll
    for (int j = 0; j < 8; ++j) {
      float v = __shfl(o[j], srcl, 64);
      t0 = ((lane & 7) == j) ? v : t0;
    }
    ((float*)dout)[(size_t)i * 64 + lane] = t0;
  }
}

// ------------------------------------------------ launcher
extern "C" void kernel_launch(void* const* d_in, const int* in_sizes, int n_in,
                              void* d_out, int out_size, void* d_ws, size_t ws_size,
                              hipStream_t stream) {
  const void* g     = d_in[0];
  const int*  edge  = (const int*)d_in[1];
  const void* Wp    = d_in[2];
  const void* attsp = d_in[3];
  const void* attdp = d_in[4];
  const void* biasp = d_in[5];

  const int D = 64;
  const int N = in_sizes[0] / D;
  const int E = in_sizes[1] / 2;
  const int* src = edge;
  const int* dst = edge + E;

  char* ws = (char*)d_ws;
  size_t off = 0;
  auto alloc = [&](size_t bytes) -> char* {
    char* p = ws + off;
    off += (bytes + 255) & ~size_t(255);
    return p;
  };
  u16*   x        = (u16*)alloc((size_t)N * D * sizeof(u16));    // 12.8 MB
  u16*   h        = (u16*)alloc((size_t)N * D * sizeof(u16));    // 12.8 MB
  float* pf       = (float*)alloc(4288 * sizeof(float));
  u16*   wfrag    = (u16*)alloc(4096 * sizeof(u16));
  float* a_src    = (float*)alloc((size_t)N * sizeof(float));
  float* a_dst    = (float*)alloc((size_t)N * sizeof(float));
  int*   deg      = (int*)alloc((size_t)N * sizeof(int));
  int*   row_off  = (int*)alloc((size_t)(N + 1) * sizeof(int));
  int*   cursor   = (int*)alloc((size_t)N * sizeof(int));
  int*   csr_src  = (int*)alloc((size_t)E * sizeof(int));        // 4 MB
  int*   partials = (int*)alloc(1024 * sizeof(int));
  int*   mode     = (int*)alloc(256);

  detect_kernel<<<1, 256, 0, stream>>>((const u32*)g, 4096, mode);

  int n64 = N * D;
  conv_x_kernel<<<(n64 + 255) / 256, 256, 0, stream>>>(g, x, n64, mode);
  conv_params_kernel<<<17, 256, 0, stream>>>(Wp, attsp, attdp, biasp, pf, mode);
  wfrag_build_kernel<<<16, 256, 0, stream>>>(pf, wfrag);

  int nper = (N + 7) / 8;  // dst ids per XCD bucket
  hipMemsetAsync(deg, 0, (size_t)N * sizeof(int), stream);
  hist_part_kernel<<<1024, 256, 0, stream>>>(dst, deg, E, nper);
  int nblk = (N + 1023) / 1024;
  scan1_kernel<<<nblk, 1024, 0, stream>>>(deg, row_off, partials, N);
  scan2_kernel<<<1, 1024, 0, stream>>>(partials, nblk);
  scan3_kernel<<<nblk, 1024, 0, stream>>>(row_off, partials, N);
  hipMemcpyAsync(cursor, row_off, (size_t)N * sizeof(int), hipMemcpyDeviceToDevice, stream);
  scatter_part_kernel<<<1024, 256, 0, stream>>>(src, dst, cursor, csr_src, E, nper);

  int ntiles = (N + 15) / 16;
  int tblocks = (ntiles + 3) / 4;  // 4 waves/block, 1 tile/wave
  for (int layer = 0; layer < 4; ++layer) {
    proj_mfma_kernel<<<tblocks, 256, 0, stream>>>(x, wfrag, pf, h, a_src, a_dst, N);
    int last = (layer == 3) ? 1 : 0;
    gather_kernel<<<(N + 3) / 4, 256, 0, stream>>>(h, a_src, a_dst, row_off, csr_src, pf,
                                                   x, d_out, N, last, mode);
  }
}